// Round 1
// baseline (317.706 us; speedup 1.0000x reference)
//
#include <hip/hip_runtime.h>
#include <stdint.h>

#define AS1 __attribute__((address_space(1)))
#define AS3 __attribute__((address_space(3)))

typedef __bf16 bf16x8 __attribute__((ext_vector_type(8)));
typedef float f32x16 __attribute__((ext_vector_type(16)));

__device__ __forceinline__ unsigned short f2bf(float f) {
  unsigned u = __float_as_uint(f);
  u += 0x7FFF + ((u >> 16) & 1);   // round-to-nearest-even
  return (unsigned short)(u >> 16);
}

// ---------------- merged fp32 -> bf16 cast for X, W_in, W_out ----------------
__global__ __launch_bounds__(256) void cast_all_kernel(const float* __restrict__ X,
                                                       const float* __restrict__ Wi,
                                                       const float* __restrict__ Wo,
                                                       unsigned short* __restrict__ out) {
  const int c1 = 2097152;            // X groups of 4
  const int c2 = 786432;             // W_in groups
  const int c3 = 262144;             // W_out groups
  int i = blockIdx.x * 256 + threadIdx.x;
  if (i >= c1 + c2 + c3) return;
  const float* src;
  int j = i;
  if (i < c1) src = X;
  else if (i < c1 + c2) { src = Wi; j = i - c1; }
  else { src = Wo; j = i - c1 - c2; }
  float4 v = reinterpret_cast<const float4*>(src)[j];
  ushort4 o;
  o.x = f2bf(v.x); o.y = f2bf(v.y); o.z = f2bf(v.z); o.w = f2bf(v.w);
  reinterpret_cast<ushort4*>(out)[i] = o;
}

// ---------------- GEMM-BT 256x(128*BNF), BK=64, 8 waves, phased K-loop ----------------
// C[m][n] = sum_k A[m][k]*B[n][k].  512 threads = 8 waves as 2(M)x4(N);
// per-wave C = 128 x (32*BNF) via 4(m) x BNF(n) fragments of 32x32x16 MFMA.
// Double-buffered LDS, global_load_lds staging with (row&7) 16B-chunk XOR swizzle.
// Per K-tile: 4 phases {ds_read subtile; lgkmcnt(0); setprio(1); 4*BNF MFMA; setprio(0)},
// ONE s_barrier + ONE vmcnt(0) drain per tile (after >=3 phases of MFMA cover);
// stage of tile t+2 issued right after the barrier (races impossible: all reads of
// that slot were lgkm-completed before the barrier).
// MODE 0: fp32 out, +bias                                  (out-proj)
// MODE 1: bf16 out, +bias; blocks bx>=8 write V^T into vt  (QKV + transpose)
// MODE 2: bf16 out = exp((mask? -1e20 : val)/32); fp32 row sums atomically into sums
// MODE 3: bf16 out = val / sums[row]                       (PV + softmax normalize)
template<int MODE, int BNF>
__global__ __launch_bounds__(512, 2) void gemm256(
    const unsigned short* __restrict__ A, long lda, long strideA,
    const unsigned short* __restrict__ B, long ldb, long strideB,
    void* __restrict__ Cv, long ldc, long strideC,
    const float* __restrict__ bias, const int* __restrict__ mask,
    float* __restrict__ sums, unsigned short* __restrict__ vt, int K) {
  static_assert(BNF == 1 || BNF == 2, "BNF must be 1 or 2");
  constexpr int BN = 128 * BNF;
  constexpr int ABYTES = 256 * 128;      // one A slot, bytes (256 rows x 64 bf16)
  constexpr int BBYTES = BN * 128;       // one B slot, bytes
  __shared__ unsigned short sA[2 * 256 * 64];
  __shared__ unsigned short sB[2 * BN * 64];
  char* sAc = (char*)sA;
  char* sBc = (char*)sB;

  const int t = threadIdx.x;
  const int lane = t & 63;
  const int wave = t >> 6;

  // T1: XCD-aware bijective block swizzle (all grids have nwg % 8 == 0)
  const int nx = gridDim.x;
  const int nwg = nx * gridDim.y;
  int orig = blockIdx.y * nx + blockIdx.x;
  int q = nwg >> 3, r8 = nwg & 7;
  int xcd = orig & 7, idx = orig >> 3;
  int wg = (xcd < r8 ? xcd * (q + 1) : r8 * (q + 1) + (xcd - r8) * q) + idx;
  const int bx = wg % nx, by = wg / nx, bz = blockIdx.z;

  const unsigned short* Ab = A + (size_t)bz * strideA + (size_t)by * 256 * lda;
  const unsigned short* Bb = B + (size_t)bz * strideB + (size_t)bx * BN * ldb;

  // staging: thread t loads 16B chunks; dest is linear (base + lane*16),
  // source column is pre-swizzled so LDS[row][chunk ^ (row&7)] = data[row][chunk]
  const int srow = t >> 3;                               // 0..63 (+ l*64)
  const int scol = ((t & 7) << 3) ^ ((srow & 7) << 3);   // elems
  const unsigned short* aS = Ab + (size_t)srow * lda + scol;
  const unsigned short* bS = Bb + (size_t)srow * ldb + scol;
  const int ldsbase = (wave << 10);

  const int NT = K >> 6;

  f32x16 acc[4][BNF];
#pragma unroll
  for (int i = 0; i < 4; i++)
#pragma unroll
    for (int j = 0; j < BNF; j++)
#pragma unroll
      for (int r = 0; r < 16; r++) acc[i][j][r] = 0.f;

  const int wm = (wave >> 2) << 7;        // 0 or 128
  const int wn = (wave & 3) * (BNF << 5); // *32 or *64
  const int r31 = lane & 31;
  const int half = lane >> 5;
  int offK[4];
#pragma unroll
  for (int ks = 0; ks < 4; ks++)
    offK[ks] = ((ks * 32 + half * 16) ^ ((r31 & 7) << 4));   // read-side swizzle

  auto stage = [&](int tk, int s) {
    const unsigned short* ap = aS + tk * 64;
#pragma unroll
    for (int l = 0; l < 4; l++)
      __builtin_amdgcn_global_load_lds((AS1 void*)(ap + (size_t)(l * 64) * lda),
                                       (AS3 void*)(sAc + s * ABYTES + ldsbase + l * 8192),
                                       16, 0, 0);
    const unsigned short* bp = bS + tk * 64;
#pragma unroll
    for (int l = 0; l < 2 * BNF; l++)
      __builtin_amdgcn_global_load_lds((AS1 void*)(bp + (size_t)(l * 64) * ldb),
                                       (AS3 void*)(sBc + s * BBYTES + ldsbase + l * 8192),
                                       16, 0, 0);
  };

  // prologue: stage tiles 0 and 1, wait only tile 0 (tile 1 stays in flight)
  stage(0, 0);
  stage(1, 1);
  if constexpr (BNF == 2) {
    asm volatile("s_waitcnt vmcnt(8)" ::: "memory");
  } else {
    asm volatile("s_waitcnt vmcnt(6)" ::: "memory");
  }
  __builtin_amdgcn_sched_barrier(0);
  __builtin_amdgcn_s_barrier();

  for (int tk = 0; tk < NT; ++tk) {
    const int s = tk & 1;
    const char* sa = sAc + s * ABYTES;
    const char* sb = sBc + s * BBYTES;
    bf16x8 bq[BNF][4];
    bf16x8 aq[4];

    // ---- phase 1: read all B frags + A m0; MFMA m0
#pragma unroll
    for (int ks = 0; ks < 4; ks++) {
#pragma unroll
      for (int j = 0; j < BNF; j++)
        bq[j][ks] = *reinterpret_cast<const bf16x8*>(sb + (wn + 32 * j + r31) * 128 + offK[ks]);
      aq[ks] = *reinterpret_cast<const bf16x8*>(sa + (wm + r31) * 128 + offK[ks]);
    }
    asm volatile("s_waitcnt lgkmcnt(0)" ::: "memory");
    __builtin_amdgcn_sched_barrier(0);
    __builtin_amdgcn_s_setprio(1);
#pragma unroll
    for (int ks = 0; ks < 4; ks++)
#pragma unroll
      for (int j = 0; j < BNF; j++)
        acc[0][j] = __builtin_amdgcn_mfma_f32_32x32x16_bf16(aq[ks], bq[j][ks], acc[0][j], 0, 0, 0);
    __builtin_amdgcn_s_setprio(0);

    // ---- phases 2,3: A m1, m2
#pragma unroll
    for (int i = 1; i <= 2; i++) {
#pragma unroll
      for (int ks = 0; ks < 4; ks++)
        aq[ks] = *reinterpret_cast<const bf16x8*>(sa + (wm + 32 * i + r31) * 128 + offK[ks]);
      asm volatile("s_waitcnt lgkmcnt(0)" ::: "memory");
      __builtin_amdgcn_sched_barrier(0);
      __builtin_amdgcn_s_setprio(1);
#pragma unroll
      for (int ks = 0; ks < 4; ks++)
#pragma unroll
        for (int j = 0; j < BNF; j++)
          acc[i][j] = __builtin_amdgcn_mfma_f32_32x32x16_bf16(aq[ks], bq[j][ks], acc[i][j], 0, 0, 0);
      __builtin_amdgcn_s_setprio(0);
    }

    // ---- phase 4: A m3 reads, then pipeline maintenance, then MFMA m3
#pragma unroll
    for (int ks = 0; ks < 4; ks++)
      aq[ks] = *reinterpret_cast<const bf16x8*>(sa + (wm + 96 + r31) * 128 + offK[ks]);
    // wait: tile t+1 staging loads done (had ~3 phases of MFMA cover) AND all
    // our ds_reads of slot s complete -> safe to overwrite slot s after barrier
    asm volatile("s_waitcnt vmcnt(0) lgkmcnt(0)" ::: "memory");
    __builtin_amdgcn_sched_barrier(0);
    __builtin_amdgcn_s_barrier();
    if (tk + 2 < NT) stage(tk + 2, s);   // flies under MFMA m3 + next tile's ph1-3
    __builtin_amdgcn_s_setprio(1);
#pragma unroll
    for (int ks = 0; ks < 4; ks++)
#pragma unroll
      for (int j = 0; j < BNF; j++)
        acc[3][j] = __builtin_amdgcn_mfma_f32_32x32x16_bf16(aq[ks], bq[j][ks], acc[3][j], 0, 0, 0);
    __builtin_amdgcn_s_setprio(0);
  }

  // ---- epilogue (same fragment layout/logic as proven 128x128 kernel) ----
  const int* mrow = (MODE == 2) ? (mask + (size_t)bz * 2048) : nullptr;
  const bool vblock = (MODE == 1) && (bx >= 8);  // QKV: n>=2048 is the V third

#pragma unroll
  for (int i = 0; i < 4; i++) {
    int gmb = by * 256 + wm + i * 32;
    float inv_r[16];
    if (MODE == 3) {
#pragma unroll
      for (int r = 0; r < 16; r++) {
        int row = (r & 3) + 8 * (r >> 2) + 4 * half;
        inv_r[r] = 1.0f / sums[(size_t)bz * 2048 + gmb + row];
      }
    }
    float rs[16];
    if (MODE == 2) {
#pragma unroll
      for (int r = 0; r < 16; r++) rs[r] = 0.f;
    }
#pragma unroll
    for (int j = 0; j < BNF; j++) {
      int gn = bx * BN + wn + j * 32 + r31;
      float bv = (MODE == 0 || MODE == 1) ? bias[gn] : 0.0f;
      if (MODE == 1 && vblock) {
        // write V^T: Vt[b][d][s], d = gn-2048, s = gmb+row
        int b = gmb >> 11;
        int sbase = gmb & 2047;
        int d = gn - 2048;
        unsigned short* vp = vt + (size_t)b * 1024 * 2048 + (size_t)d * 2048 + sbase + 4 * half;
#pragma unroll
        for (int qd = 0; qd < 4; qd++) {
          ushort4 o;
          o.x = f2bf(acc[i][j][4 * qd + 0] + bv);
          o.y = f2bf(acc[i][j][4 * qd + 1] + bv);
          o.z = f2bf(acc[i][j][4 * qd + 2] + bv);
          o.w = f2bf(acc[i][j][4 * qd + 3] + bv);
          *reinterpret_cast<ushort4*>(vp + 8 * qd) = o;
        }
      } else {
        bool msk = (MODE == 2) ? (mrow[gn] == 0) : false;
#pragma unroll
        for (int r = 0; r < 16; r++) {
          int row = (r & 3) + 8 * (r >> 2) + 4 * half;
          float val = acc[i][j][r] + bv;
          size_t off = (size_t)bz * strideC + (size_t)(gmb + row) * ldc + gn;
          if (MODE == 2) {
            if (msk) val = -1e20f;
            val = __expf(val * 0.03125f);  // mask BEFORE 1/sqrt(1024) scale, per ref
            rs[r] += val;
            ((unsigned short*)Cv)[off] = f2bf(val);
          } else if (MODE == 3) {
            ((unsigned short*)Cv)[off] = f2bf(val * inv_r[r]);
          } else if (MODE == 1) {
            ((unsigned short*)Cv)[off] = f2bf(val);
          } else {
            ((float*)Cv)[off] = val;
          }
        }
      }
    }
    if (MODE == 2) {
      // reduce rs over the 32 column-lanes (r31), one atomicAdd per row
      float* srowp = sums + (size_t)bz * 2048;
#pragma unroll
      for (int r = 0; r < 16; r++) {
        float v = rs[r];
#pragma unroll
        for (int o = 16; o >= 1; o >>= 1) v += __shfl_xor(v, o, 64);
        if (r31 == 0) {
          int row = (r & 3) + 8 * (r >> 2) + 4 * half;
          atomicAdd(&srowp[gmb + row], v);
        }
      }
    }
  }
}

extern "C" void kernel_launch(void* const* d_in, const int* in_sizes, int n_in,
                              void* d_out, int out_size, void* d_ws, size_t ws_size,
                              hipStream_t stream) {
  const float* X = (const float*)d_in[0];
  const int* mask = (const int*)d_in[1];
  const float* W_in = (const float*)d_in[2];
  const float* b_in = (const float*)d_in[3];
  const float* W_out = (const float*)d_in[4];
  const float* b_out = (const float*)d_in[5];
  float* out = (float*)d_out;

  const int S = 2048;
  // ws layout (bytes):
  //   Xb  [8192x1024] bf16  16777216  (reused as Ob after QKV)
  //   Wib [3072x1024] bf16   6291456
  //   Wob [1024x1024] bf16   2097152
  //   QK  [8192x2048] bf16  33554432  (Q cols 0..1023, K cols 1024..2047)
  //   P   [4x2048x2048] bf16 33554432 (unnormalized exp weights)
  //   Vt  [4x1024x2048] bf16 16777216
  //   sums[8192] f32            32768
  char* w = (char*)d_ws;
  unsigned short* Xb  = (unsigned short*)w;
  unsigned short* Wib = (unsigned short*)(w + 16777216);
  unsigned short* Wob = (unsigned short*)(w + 16777216 + 6291456);
  unsigned short* QK  = (unsigned short*)(w + 25165824);
  unsigned short* P   = (unsigned short*)(w + 58720256);
  unsigned short* Vt  = (unsigned short*)(w + 92274688);
  float*          sums = (float*)(w + 109051904);
  unsigned short* Ob  = Xb;

  // zero the row-sum accumulators (ws is re-poisoned before every call)
  hipMemsetAsync(sums, 0, 8192 * sizeof(float), stream);

  // one merged cast: X, W_in, W_out -> bf16 (outputs contiguous)
  cast_all_kernel<<<12288, 256, 0, stream>>>(X, W_in, W_out, Xb);

  // QKV = Xb @ W_in^T + b_in; Q,K -> QK[8192x2048], V -> Vt (transposed in epilogue)
  // 256x256 tiles: grid 12 x 32 = 384 blocks
  gemm256<1, 2><<<dim3(12, 32, 1), 512, 0, stream>>>(
      Xb, 1024, 0, Wib, 1024, 0, QK, 2048, 0, b_in, nullptr, nullptr, Vt, 1024);
  // P = exp(mask(Q K^T)/32); sums += fp32 row sums   [per batch 2048x2048]
  // 256x256 tiles: grid 8 x 8 x 4 = 256 blocks
  gemm256<2, 2><<<dim3(8, 8, 4), 512, 0, stream>>>(
      QK, 2048, (long)S * 2048, QK + 1024, 2048, (long)S * 2048,
      P, 2048, (long)S * S, nullptr, mask, sums, nullptr, 1024);
  // O = (P @ Vt^T) / sums   [per batch 2048x1024] bf16
  // 256x128 tiles: grid 8 x 8 x 4 = 256 blocks (keeps all CUs busy at N=1024)
  gemm256<3, 1><<<dim3(8, 8, 4), 512, 0, stream>>>(
      P, 2048, (long)S * S, Vt, 2048, (long)1024 * 2048,
      Ob, 1024, (long)S * 1024, nullptr, nullptr, sums, nullptr, 2048);
  // out = O @ W_out^T + b_out  [8192x1024] fp32
  // 256x128 tiles: grid 8 x 32 = 256 blocks
  gemm256<0, 1><<<dim3(8, 32, 1), 512, 0, stream>>>(
      Ob, 1024, 0, Wob, 1024, 0, out, 1024, 0, b_out, nullptr, nullptr, nullptr, 1024);
}

// Round 2
// 314.993 us; speedup vs baseline: 1.0086x; 1.0086x over previous
//
#include <hip/hip_runtime.h>
#include <stdint.h>

#define AS1 __attribute__((address_space(1)))
#define AS3 __attribute__((address_space(3)))

typedef __bf16 bf16x8 __attribute__((ext_vector_type(8)));
typedef float f32x16 __attribute__((ext_vector_type(16)));

__device__ __forceinline__ unsigned short f2bf(float f) {
  unsigned u = __float_as_uint(f);
  u += 0x7FFF + ((u >> 16) & 1);   // round-to-nearest-even
  return (unsigned short)(u >> 16);
}

// ---------------- merged fp32 -> bf16 cast for X, W_in, W_out ----------------
__global__ __launch_bounds__(256) void cast_all_kernel(const float* __restrict__ X,
                                                       const float* __restrict__ Wi,
                                                       const float* __restrict__ Wo,
                                                       unsigned short* __restrict__ out) {
  const int c1 = 2097152;            // X groups of 4
  const int c2 = 786432;             // W_in groups
  const int c3 = 262144;             // W_out groups
  int i = blockIdx.x * 256 + threadIdx.x;
  if (i >= c1 + c2 + c3) return;
  const float* src;
  int j = i;
  if (i < c1) src = X;
  else if (i < c1 + c2) { src = Wi; j = i - c1; }
  else { src = Wo; j = i - c1 - c2; }
  float4 v = reinterpret_cast<const float4*>(src)[j];
  ushort4 o;
  o.x = f2bf(v.x); o.y = f2bf(v.y); o.z = f2bf(v.z); o.w = f2bf(v.w);
  reinterpret_cast<ushort4*>(out)[i] = o;
}

// ================= gemmQ: 256x256, BK=32, QUAD-buffered LDS ring, counted vmcnt =================
// C[m][n] = sum_k A[m][k]*B[n][k].  512 threads = 8 waves (2M x 4N), per-wave C = 128x64
// as 4(m) x 2(n) frags of 32x32x16 MFMA.  LDS: 4 slots x (A 16KB + B 16KB) = 128 KB.
// Pipeline: slots form a ring; stage(t+3) issued after the end-of-tile-t barrier, so
// 2 tiles of loads (8 per wave) stay in flight across every barrier; the per-tile wait
// is vmcnt(4) (tile t+1 landed, t+2 still flying) -- never a vmcnt(0) drain in steady state.
// Race-freedom: reads of slot s complete (data-dep lgkm waits) before tile s's MFMAs,
// which precede TWO barriers before any stage() targets slot s again (ring distance 4,
// stage issued 3 ahead).  vmcnt(4) sits BEFORE the barrier so every wave publishes its
// own staged data first.
// MODE 1: bf16 out, +bias; blocks bx>=8 write V^T into vt  (QKV + transpose)
// MODE 2: bf16 out = exp((mask? -1e20 : val)/32); fp32 row sums atomically into sums
template<int MODE>
__global__ __launch_bounds__(512, 2) void gemmQ(
    const unsigned short* __restrict__ A, long lda, long strideA,
    const unsigned short* __restrict__ B, long ldb, long strideB,
    void* __restrict__ Cv, long ldc, long strideC,
    const float* __restrict__ bias, const int* __restrict__ mask,
    float* __restrict__ sums, unsigned short* __restrict__ vt, int K) {
  __shared__ unsigned short sAll[65536];   // 128 KB: 4 slots x 32 KB (A 16KB | B 16KB)
  char* sBase = (char*)sAll;
  const int t = threadIdx.x;
  const int lane = t & 63;
  const int wave = t >> 6;

  // T1: XCD-aware bijective block swizzle (nwg % 8 == 0 for all our grids)
  const int nx = gridDim.x;
  const int nwg = nx * gridDim.y;
  int orig = blockIdx.y * nx + blockIdx.x;
  int q = nwg >> 3, r8 = nwg & 7;
  int xcd = orig & 7, idx = orig >> 3;
  int wg = (xcd < r8 ? xcd * (q + 1) : r8 * (q + 1) + (xcd - r8) * q) + idx;
  const int bx = wg % nx, by = wg / nx, bz = blockIdx.z;

  const unsigned short* Ab = A + (size_t)bz * strideA + (size_t)by * 256 * lda;
  const unsigned short* Bb = B + (size_t)bz * strideB + (size_t)bx * 256 * ldb;

  // staging: rows of 32 bf16 (64 B = 4 chunks of 16B). thread t -> row t>>2, chunk t&3,
  // two rounds of 128 rows.  dest is linear (wave-uniform base + lane*16); the SOURCE
  // column is pre-swizzled: LDS[row][c] = src[row][c ^ ((row>>1)&3)].
  const int srow = t >> 2;                                  // 0..127
  const int scol = ((t & 3) ^ ((srow >> 1) & 3)) << 3;      // elems
  const unsigned short* aS = Ab + (size_t)srow * lda + scol;
  const unsigned short* bS = Bb + (size_t)srow * ldb + scol;

  auto stage = [&](int tk, int s) {
    char* base = sBase + s * 32768 + wave * 1024;
    const unsigned short* ap = aS + tk * 32;
    const unsigned short* bp = bS + tk * 32;
#pragma unroll
    for (int l = 0; l < 2; l++)
      __builtin_amdgcn_global_load_lds((AS1 void*)(ap + (size_t)(l * 128) * lda),
                                       (AS3 void*)(base + l * 8192), 16, 0, 0);
#pragma unroll
    for (int l = 0; l < 2; l++)
      __builtin_amdgcn_global_load_lds((AS1 void*)(bp + (size_t)(l * 128) * ldb),
                                       (AS3 void*)(base + 16384 + l * 8192), 16, 0, 0);
  };

  const int NT = K >> 5;          // K/32 tiles (>= 32 for all our shapes)

  f32x16 acc[4][2];
#pragma unroll
  for (int i = 0; i < 4; i++)
#pragma unroll
    for (int j = 0; j < 2; j++)
#pragma unroll
      for (int r = 0; r < 16; r++) acc[i][j][r] = 0.f;

  const int wm = (wave >> 2) << 7;   // 0 / 128
  const int wn = (wave & 3) << 6;    // 0 / 64 / 128 / 192
  const int r31 = lane & 31;
  const int half = lane >> 5;
  const int swz2 = (r31 >> 1) & 3;
  int offC[2];
#pragma unroll
  for (int ks = 0; ks < 2; ks++)
    offC[ks] = ((((ks << 1) + half) ^ swz2) << 4);          // byte offset within row
  int rowA[4], rowB[2];
#pragma unroll
  for (int i = 0; i < 4; i++) rowA[i] = (wm + 32 * i + r31) << 6;
#pragma unroll
  for (int j = 0; j < 2; j++) rowB[j] = (wn + 32 * j + r31) << 6;

  // prologue: 3 tiles staged (12 loads in flight), wait only tile 0 (8 stay flying)
  stage(0, 0);
  stage(1, 1);
  stage(2, 2);
  asm volatile("s_waitcnt vmcnt(8)" ::: "memory");
  __builtin_amdgcn_sched_barrier(0);
  __builtin_amdgcn_s_barrier();
  __builtin_amdgcn_sched_barrier(0);

  for (int tk = 0; tk < NT; ++tk) {
    const char* sa = sBase + (tk & 3) * 32768;
    const char* sb = sa + 16384;
    bf16x8 aq0[2], aq1[2], aq2[2], aq3[2], bq0[2], bq1[2];
#pragma unroll
    for (int ks = 0; ks < 2; ks++) {
      bq0[ks] = *reinterpret_cast<const bf16x8*>(sb + rowB[0] + offC[ks]);
      bq1[ks] = *reinterpret_cast<const bf16x8*>(sb + rowB[1] + offC[ks]);
      aq0[ks] = *reinterpret_cast<const bf16x8*>(sa + rowA[0] + offC[ks]);
      aq1[ks] = *reinterpret_cast<const bf16x8*>(sa + rowA[1] + offC[ks]);
      aq2[ks] = *reinterpret_cast<const bf16x8*>(sa + rowA[2] + offC[ks]);
      aq3[ks] = *reinterpret_cast<const bf16x8*>(sa + rowA[3] + offC[ks]);
    }
    __builtin_amdgcn_s_setprio(1);
#pragma unroll
    for (int ks = 0; ks < 2; ks++) {
      acc[0][0] = __builtin_amdgcn_mfma_f32_32x32x16_bf16(aq0[ks], bq0[ks], acc[0][0], 0, 0, 0);
      acc[0][1] = __builtin_amdgcn_mfma_f32_32x32x16_bf16(aq0[ks], bq1[ks], acc[0][1], 0, 0, 0);
      acc[1][0] = __builtin_amdgcn_mfma_f32_32x32x16_bf16(aq1[ks], bq0[ks], acc[1][0], 0, 0, 0);
      acc[1][1] = __builtin_amdgcn_mfma_f32_32x32x16_bf16(aq1[ks], bq1[ks], acc[1][1], 0, 0, 0);
      acc[2][0] = __builtin_amdgcn_mfma_f32_32x32x16_bf16(aq2[ks], bq0[ks], acc[2][0], 0, 0, 0);
      acc[2][1] = __builtin_amdgcn_mfma_f32_32x32x16_bf16(aq2[ks], bq1[ks], acc[2][1], 0, 0, 0);
      acc[3][0] = __builtin_amdgcn_mfma_f32_32x32x16_bf16(aq3[ks], bq0[ks], acc[3][0], 0, 0, 0);
      acc[3][1] = __builtin_amdgcn_mfma_f32_32x32x16_bf16(aq3[ks], bq1[ks], acc[3][1], 0, 0, 0);
    }
    __builtin_amdgcn_s_setprio(0);
    if (tk == NT - 1) break;
    __builtin_amdgcn_sched_barrier(0);
    if (tk + 2 < NT) { asm volatile("s_waitcnt vmcnt(4)" ::: "memory"); }
    else             { asm volatile("s_waitcnt vmcnt(0)" ::: "memory"); }
    __builtin_amdgcn_sched_barrier(0);
    __builtin_amdgcn_s_barrier();
    __builtin_amdgcn_sched_barrier(0);
    if (tk + 3 < NT) stage(tk + 3, (tk + 3) & 3);
  }

  // ---- epilogue (proven fragment layout: col = lane&31 -> n, row = (r&3)+8*(r>>2)+4*half) ----
  const int* mrow = (MODE == 2) ? (mask + (size_t)bz * 2048) : nullptr;
  const bool vblock = (MODE == 1) && (bx >= 8);  // QKV: n>=2048 is the V third

#pragma unroll
  for (int i = 0; i < 4; i++) {
    int gmb = by * 256 + wm + i * 32;
    float rs[16];
    if (MODE == 2) {
#pragma unroll
      for (int r = 0; r < 16; r++) rs[r] = 0.f;
    }
#pragma unroll
    for (int j = 0; j < 2; j++) {
      int gn = bx * 256 + wn + j * 32 + r31;
      float bv = (MODE == 1) ? bias[gn] : 0.0f;
      if (MODE == 1 && vblock) {
        // write V^T: Vt[b][d][s], d = gn-2048, s = gmb+row
        int b = gmb >> 11;
        int sbase = gmb & 2047;
        int d = gn - 2048;
        unsigned short* vp = vt + (size_t)b * 1024 * 2048 + (size_t)d * 2048 + sbase + 4 * half;
#pragma unroll
        for (int qd = 0; qd < 4; qd++) {
          ushort4 o;
          o.x = f2bf(acc[i][j][4 * qd + 0] + bv);
          o.y = f2bf(acc[i][j][4 * qd + 1] + bv);
          o.z = f2bf(acc[i][j][4 * qd + 2] + bv);
          o.w = f2bf(acc[i][j][4 * qd + 3] + bv);
          *reinterpret_cast<ushort4*>(vp + 8 * qd) = o;
        }
      } else {
        bool msk = (MODE == 2) ? (mrow[gn] == 0) : false;
#pragma unroll
        for (int r = 0; r < 16; r++) {
          int row = (r & 3) + 8 * (r >> 2) + 4 * half;
          float val = acc[i][j][r] + bv;
          size_t off = (size_t)bz * strideC + (size_t)(gmb + row) * ldc + gn;
          if (MODE == 2) {
            if (msk) val = -1e20f;
            val = __expf(val * 0.03125f);  // mask BEFORE 1/sqrt(1024) scale, per ref
            rs[r] += val;
            ((unsigned short*)Cv)[off] = f2bf(val);
          } else {
            ((unsigned short*)Cv)[off] = f2bf(val);
          }
        }
      }
    }
    if (MODE == 2) {
      float* srowp = sums + (size_t)bz * 2048;
#pragma unroll
      for (int r = 0; r < 16; r++) {
        float v = rs[r];
#pragma unroll
        for (int o = 16; o >= 1; o >>= 1) v += __shfl_xor(v, o, 64);
        if (r31 == 0) {
          int row = (r & 3) + 8 * (r >> 2) + 4 * half;
          atomicAdd(&srowp[gmb + row], v);
        }
      }
    }
  }
}

// ================= proven 128x128 kernel (R0 baseline) for PV + out-proj =================
template<int MODE>
__global__ __launch_bounds__(256, 2) void gemm_bt128(
    const unsigned short* __restrict__ A, long lda, long strideA,
    const unsigned short* __restrict__ B, long ldb, long strideB,
    void* __restrict__ Cv, long ldc, long strideC,
    const float* __restrict__ bias, const int* __restrict__ mask,
    float* __restrict__ sums, unsigned short* __restrict__ vt, int K) {
  __shared__ unsigned short sA[128 * 64];
  __shared__ unsigned short sB[128 * 64];
  const int t = threadIdx.x;
  const int lane = t & 63;
  const int wave = t >> 6;

  const unsigned short* Ab = A + (size_t)blockIdx.z * strideA + (size_t)blockIdx.y * 128 * lda;
  const unsigned short* Bb = B + (size_t)blockIdx.z * strideB + (size_t)blockIdx.x * 128 * ldb;

  const int srow = t >> 3;
  const int schunk = (t & 7) ^ (srow & 7);
  const unsigned short* aptr = Ab + (size_t)srow * lda + schunk * 8;
  const unsigned short* bptr = Bb + (size_t)srow * ldb + schunk * 8;
  char* ldsA0 = (char*)&sA[0] + wave * 1024;
  char* ldsB0 = (char*)&sB[0] + wave * 1024;

  f32x16 acc[2][2];
#pragma unroll
  for (int i = 0; i < 2; i++)
#pragma unroll
    for (int j = 0; j < 2; j++)
#pragma unroll
      for (int r = 0; r < 16; r++) acc[i][j][r] = 0.f;

  const int wm = (wave >> 1) * 64;
  const int wn = (wave & 1) * 64;
  const int r31 = lane & 31;
  const int half = lane >> 5;
  const int swz = r31 & 7;

  int offA[2][4], offB[2][4];
#pragma unroll
  for (int i = 0; i < 2; i++)
#pragma unroll
    for (int s = 0; s < 4; s++) {
      offA[i][s] = (wm + i * 32 + r31) * 128 + (((2 * s + half) ^ swz) * 16);
      offB[i][s] = (wn + i * 32 + r31) * 128 + (((2 * s + half) ^ swz) * 16);
    }

  for (int k0 = 0; k0 < K; k0 += 64) {
    __syncthreads();
#pragma unroll
    for (int o = 0; o < 4; o++) {
      __builtin_amdgcn_global_load_lds((AS1 void*)(aptr + (size_t)o * 32 * lda + k0),
                                       (AS3 void*)(ldsA0 + o * 4096), 16, 0, 0);
      __builtin_amdgcn_global_load_lds((AS1 void*)(bptr + (size_t)o * 32 * ldb + k0),
                                       (AS3 void*)(ldsB0 + o * 4096), 16, 0, 0);
    }
    __syncthreads();
#pragma unroll
    for (int s = 0; s < 4; s++) {
      bf16x8 af[2], bfv[2];
#pragma unroll
      for (int i = 0; i < 2; i++) {
        af[i]  = *reinterpret_cast<const bf16x8*>((const char*)sA + offA[i][s]);
        bfv[i] = *reinterpret_cast<const bf16x8*>((const char*)sB + offB[i][s]);
      }
#pragma unroll
      for (int i = 0; i < 2; i++)
#pragma unroll
        for (int j = 0; j < 2; j++)
          acc[i][j] = __builtin_amdgcn_mfma_f32_32x32x16_bf16(af[i], bfv[j], acc[i][j], 0, 0, 0);
    }
  }

  // ---- epilogue ----
#pragma unroll
  for (int i = 0; i < 2; i++) {
    int gmb = blockIdx.y * 128 + wm + i * 32;
    float inv_r[16];
    if (MODE == 3) {
#pragma unroll
      for (int r = 0; r < 16; r++) {
        int row = (r & 3) + 8 * (r >> 2) + 4 * half;
        inv_r[r] = 1.0f / sums[(size_t)blockIdx.z * 2048 + gmb + row];
      }
    }
#pragma unroll
    for (int j = 0; j < 2; j++) {
      int gn = blockIdx.x * 128 + wn + j * 32 + r31;
      float bv = (MODE == 0) ? bias[gn] : 0.0f;
#pragma unroll
      for (int r = 0; r < 16; r++) {
        int row = (r & 3) + 8 * (r >> 2) + 4 * half;
        float val = acc[i][j][r] + bv;
        size_t off = (size_t)blockIdx.z * strideC + (size_t)(gmb + row) * ldc + gn;
        if (MODE == 3) {
          ((unsigned short*)Cv)[off] = f2bf(val * inv_r[r]);
        } else {
          ((float*)Cv)[off] = val;
        }
      }
    }
  }
}

extern "C" void kernel_launch(void* const* d_in, const int* in_sizes, int n_in,
                              void* d_out, int out_size, void* d_ws, size_t ws_size,
                              hipStream_t stream) {
  const float* X = (const float*)d_in[0];
  const int* mask = (const int*)d_in[1];
  const float* W_in = (const float*)d_in[2];
  const float* b_in = (const float*)d_in[3];
  const float* W_out = (const float*)d_in[4];
  const float* b_out = (const float*)d_in[5];
  float* out = (float*)d_out;

  const int S = 2048, D = 1024;
  // ws layout (bytes):
  //   Xb  [8192x1024] bf16  16777216  (reused as Ob after QKV)
  //   Wib [3072x1024] bf16   6291456
  //   Wob [1024x1024] bf16   2097152
  //   QK  [8192x2048] bf16  33554432  (Q cols 0..1023, K cols 1024..2047)
  //   P   [4x2048x2048] bf16 33554432 (unnormalized exp weights)
  //   Vt  [4x1024x2048] bf16 16777216
  //   sums[8192] f32            32768
  char* w = (char*)d_ws;
  unsigned short* Xb  = (unsigned short*)w;
  unsigned short* Wib = (unsigned short*)(w + 16777216);
  unsigned short* Wob = (unsigned short*)(w + 16777216 + 6291456);
  unsigned short* QK  = (unsigned short*)(w + 25165824);
  unsigned short* P   = (unsigned short*)(w + 58720256);
  unsigned short* Vt  = (unsigned short*)(w + 92274688);
  float*          sums = (float*)(w + 109051904);
  unsigned short* Ob  = Xb;

  // zero the row-sum accumulators (ws is re-poisoned before every call)
  hipMemsetAsync(sums, 0, 8192 * sizeof(float), stream);

  // one merged cast: X, W_in, W_out -> bf16 (outputs contiguous)
  cast_all_kernel<<<12288, 256, 0, stream>>>(X, W_in, W_out, Xb);

  // QKV = Xb @ W_in^T + b_in; Q,K -> QK[8192x2048], V -> Vt (transposed in epilogue)
  // 256x256 tiles, quad-buffered: grid 12 x 32 = 384 blocks
  gemmQ<1><<<dim3(12, 32, 1), 512, 0, stream>>>(
      Xb, D, 0, Wib, D, 0, QK, 2048, 0, b_in, nullptr, nullptr, Vt, D);
  // P = exp(mask(Q K^T)/32); sums += fp32 row sums   [per batch 2048x2048]
  // 256x256 tiles: grid 8 x 8 x 4 = 256 blocks
  gemmQ<2><<<dim3(8, 8, 4), 512, 0, stream>>>(
      QK, 2048, (long)S * 2048, QK + 1024, 2048, (long)S * 2048,
      P, S, (long)S * S, nullptr, mask, sums, nullptr, D);
  // O = (P @ Vt^T) / sums   [per batch 2048x1024] bf16  (proven 128x128 kernel)
  gemm_bt128<3><<<dim3(8, 16, 4), 256, 0, stream>>>(
      P, S, (long)S * S, Vt, S, (long)D * S,
      Ob, D, (long)S * D, nullptr, nullptr, sums, nullptr, S);
  // out = O @ W_out^T + b_out  [8192x1024] fp32  (proven 128x128 kernel)
  gemm_bt128<0><<<dim3(8, 64, 1), 256, 0, stream>>>(
      Ob, D, 0, Wob, D, 0, out, D, 0, b_out, nullptr, nullptr, nullptr, D);
}

// Round 3
// 307.989 us; speedup vs baseline: 1.0315x; 1.0227x over previous
//
#include <hip/hip_runtime.h>
#include <stdint.h>

#define AS1 __attribute__((address_space(1)))
#define AS3 __attribute__((address_space(3)))

typedef __bf16 bf16x8 __attribute__((ext_vector_type(8)));
typedef float f32x16 __attribute__((ext_vector_type(16)));

__device__ __forceinline__ unsigned short f2bf(float f) {
  unsigned u = __float_as_uint(f);
  u += 0x7FFF + ((u >> 16) & 1);   // round-to-nearest-even
  return (unsigned short)(u >> 16);
}

// ---------------- merged fp32 -> bf16 cast for X, W_in, W_out ----------------
__global__ __launch_bounds__(256) void cast_all_kernel(const float* __restrict__ X,
                                                       const float* __restrict__ Wi,
                                                       const float* __restrict__ Wo,
                                                       unsigned short* __restrict__ out) {
  const int c1 = 2097152;            // X groups of 4
  const int c2 = 786432;             // W_in groups
  const int c3 = 262144;             // W_out groups
  int i = blockIdx.x * 256 + threadIdx.x;
  if (i >= c1 + c2 + c3) return;
  const float* src;
  int j = i;
  if (i < c1) src = X;
  else if (i < c1 + c2) { src = Wi; j = i - c1; }
  else { src = Wo; j = i - c1 - c2; }
  float4 v = reinterpret_cast<const float4*>(src)[j];
  ushort4 o;
  o.x = f2bf(v.x); o.y = f2bf(v.y); o.z = f2bf(v.z); o.w = f2bf(v.w);
  reinterpret_cast<ushort4*>(out)[i] = o;
}

// ================= gemmQ: 256x256, BK=32, QUAD-buffered LDS ring, counted vmcnt =================
// Swizzle (R3 fix): 256-B-group conflict-free. LDS rows are 64 B (4 slots of 16 B).
// slot s of row r holds data chunk s ^ ((r>>2)&3); a 16-lane read group (16 consecutive
// rows) then covers all 16 combos of (row&3, slot) = 256 distinct bytes -> no 2-way
// conflict at the 256 B/clock LDS port.
// MODE 1: bf16 out, +bias; blocks bx>=8 write V^T into vt  (QKV + transpose)
// MODE 2: bf16 out = exp((mask? -1e20 : val)/32); fp32 row sums atomically into sums
template<int MODE>
__global__ __launch_bounds__(512, 2) void gemmQ(
    const unsigned short* __restrict__ A, long lda, long strideA,
    const unsigned short* __restrict__ B, long ldb, long strideB,
    void* __restrict__ Cv, long ldc, long strideC,
    const float* __restrict__ bias, const int* __restrict__ mask,
    float* __restrict__ sums, unsigned short* __restrict__ vt, int K) {
  __shared__ unsigned short sAll[65536];   // 128 KB: 4 slots x 32 KB (A 16KB | B 16KB)
  char* sBase = (char*)sAll;
  const int t = threadIdx.x;
  const int lane = t & 63;
  const int wave = t >> 6;

  // T1: XCD-aware bijective block swizzle (nwg % 8 == 0 for all our grids)
  const int nx = gridDim.x;
  const int nwg = nx * gridDim.y;
  int orig = blockIdx.y * nx + blockIdx.x;
  int q = nwg >> 3, r8 = nwg & 7;
  int xcd = orig & 7, idx = orig >> 3;
  int wg = (xcd < r8 ? xcd * (q + 1) : r8 * (q + 1) + (xcd - r8) * q) + idx;
  const int bx = wg % nx, by = wg / nx, bz = blockIdx.z;

  const unsigned short* Ab = A + (size_t)bz * strideA + (size_t)by * 256 * lda;
  const unsigned short* Bb = B + (size_t)bz * strideB + (size_t)bx * 256 * ldb;

  // staging: rows of 32 bf16 (64 B = 4 chunks of 16B). thread t -> row t>>2, chunk t&3,
  // dest linear (wave-uniform base + lane*16); SOURCE column pre-swizzled:
  // LDS slot c of row r = src chunk c ^ ((r>>2)&3).
  const int srow = t >> 2;                                  // 0..127
  const int scol = ((t & 3) ^ ((srow >> 2) & 3)) << 3;      // elems
  const unsigned short* aS = Ab + (size_t)srow * lda + scol;
  const unsigned short* bS = Bb + (size_t)srow * ldb + scol;

  auto stage = [&](int tk, int s) {
    char* base = sBase + s * 32768 + wave * 1024;
    const unsigned short* ap = aS + tk * 32;
    const unsigned short* bp = bS + tk * 32;
#pragma unroll
    for (int l = 0; l < 2; l++)
      __builtin_amdgcn_global_load_lds((AS1 void*)(ap + (size_t)(l * 128) * lda),
                                       (AS3 void*)(base + l * 8192), 16, 0, 0);
#pragma unroll
    for (int l = 0; l < 2; l++)
      __builtin_amdgcn_global_load_lds((AS1 void*)(bp + (size_t)(l * 128) * ldb),
                                       (AS3 void*)(base + 16384 + l * 8192), 16, 0, 0);
  };

  const int NT = K >> 5;          // K/32 tiles

  f32x16 acc[4][2];
#pragma unroll
  for (int i = 0; i < 4; i++)
#pragma unroll
    for (int j = 0; j < 2; j++)
#pragma unroll
      for (int r = 0; r < 16; r++) acc[i][j][r] = 0.f;

  const int wm = (wave >> 2) << 7;   // 0 / 128
  const int wn = (wave & 3) << 6;    // 0 / 64 / 128 / 192
  const int r31 = lane & 31;
  const int half = lane >> 5;
  const int swz = (r31 >> 2) & 3;    // R3: row-quad swizzle (was (r31>>1)&3)
  int offC[2];
#pragma unroll
  for (int ks = 0; ks < 2; ks++)
    offC[ks] = ((((ks << 1) + half) ^ swz) << 4);           // byte offset within row
  int rowA[4], rowB[2];
#pragma unroll
  for (int i = 0; i < 4; i++) rowA[i] = (wm + 32 * i + r31) << 6;
#pragma unroll
  for (int j = 0; j < 2; j++) rowB[j] = (wn + 32 * j + r31) << 6;

  // prologue: 3 tiles staged (12 loads in flight), wait only tile 0 (8 stay flying)
  stage(0, 0);
  stage(1, 1);
  stage(2, 2);
  asm volatile("s_waitcnt vmcnt(8)" ::: "memory");
  __builtin_amdgcn_sched_barrier(0);
  __builtin_amdgcn_s_barrier();
  __builtin_amdgcn_sched_barrier(0);

  for (int tk = 0; tk < NT; ++tk) {
    const char* sa = sBase + (tk & 3) * 32768;
    const char* sb = sa + 16384;
    bf16x8 aq0[2], aq1[2], aq2[2], aq3[2], bq0[2], bq1[2];
#pragma unroll
    for (int ks = 0; ks < 2; ks++) {
      bq0[ks] = *reinterpret_cast<const bf16x8*>(sb + rowB[0] + offC[ks]);
      bq1[ks] = *reinterpret_cast<const bf16x8*>(sb + rowB[1] + offC[ks]);
      aq0[ks] = *reinterpret_cast<const bf16x8*>(sa + rowA[0] + offC[ks]);
      aq1[ks] = *reinterpret_cast<const bf16x8*>(sa + rowA[1] + offC[ks]);
      aq2[ks] = *reinterpret_cast<const bf16x8*>(sa + rowA[2] + offC[ks]);
      aq3[ks] = *reinterpret_cast<const bf16x8*>(sa + rowA[3] + offC[ks]);
    }
    __builtin_amdgcn_s_setprio(1);
#pragma unroll
    for (int ks = 0; ks < 2; ks++) {
      acc[0][0] = __builtin_amdgcn_mfma_f32_32x32x16_bf16(aq0[ks], bq0[ks], acc[0][0], 0, 0, 0);
      acc[0][1] = __builtin_amdgcn_mfma_f32_32x32x16_bf16(aq0[ks], bq1[ks], acc[0][1], 0, 0, 0);
      acc[1][0] = __builtin_amdgcn_mfma_f32_32x32x16_bf16(aq1[ks], bq0[ks], acc[1][0], 0, 0, 0);
      acc[1][1] = __builtin_amdgcn_mfma_f32_32x32x16_bf16(aq1[ks], bq1[ks], acc[1][1], 0, 0, 0);
      acc[2][0] = __builtin_amdgcn_mfma_f32_32x32x16_bf16(aq2[ks], bq0[ks], acc[2][0], 0, 0, 0);
      acc[2][1] = __builtin_amdgcn_mfma_f32_32x32x16_bf16(aq2[ks], bq1[ks], acc[2][1], 0, 0, 0);
      acc[3][0] = __builtin_amdgcn_mfma_f32_32x32x16_bf16(aq3[ks], bq0[ks], acc[3][0], 0, 0, 0);
      acc[3][1] = __builtin_amdgcn_mfma_f32_32x32x16_bf16(aq3[ks], bq1[ks], acc[3][1], 0, 0, 0);
    }
    __builtin_amdgcn_s_setprio(0);
    if (tk == NT - 1) break;
    __builtin_amdgcn_sched_barrier(0);
    if (tk + 2 < NT) { asm volatile("s_waitcnt vmcnt(4)" ::: "memory"); }
    else             { asm volatile("s_waitcnt vmcnt(0)" ::: "memory"); }
    __builtin_amdgcn_sched_barrier(0);
    __builtin_amdgcn_s_barrier();
    __builtin_amdgcn_sched_barrier(0);
    if (tk + 3 < NT) stage(tk + 3, (tk + 3) & 3);
  }

  // ---- epilogue (fragment layout: col = lane&31 -> n, row = (r&3)+8*(r>>2)+4*half) ----
  const int* mrow = (MODE == 2) ? (mask + (size_t)bz * 2048) : nullptr;
  const bool vblock = (MODE == 1) && (bx >= 8);  // QKV: n>=2048 is the V third

#pragma unroll
  for (int i = 0; i < 4; i++) {
    int gmb = by * 256 + wm + i * 32;
    float rs[16];
    if (MODE == 2) {
#pragma unroll
      for (int r = 0; r < 16; r++) rs[r] = 0.f;
    }
#pragma unroll
    for (int j = 0; j < 2; j++) {
      int gn = bx * 256 + wn + j * 32 + r31;
      float bv = (MODE == 1) ? bias[gn] : 0.0f;
      if (MODE == 1 && vblock) {
        // write V^T: Vt[b][d][s], d = gn-2048, s = gmb+row
        int b = gmb >> 11;
        int sbase = gmb & 2047;
        int d = gn - 2048;
        unsigned short* vp = vt + (size_t)b * 1024 * 2048 + (size_t)d * 2048 + sbase + 4 * half;
#pragma unroll
        for (int qd = 0; qd < 4; qd++) {
          ushort4 o;
          o.x = f2bf(acc[i][j][4 * qd + 0] + bv);
          o.y = f2bf(acc[i][j][4 * qd + 1] + bv);
          o.z = f2bf(acc[i][j][4 * qd + 2] + bv);
          o.w = f2bf(acc[i][j][4 * qd + 3] + bv);
          *reinterpret_cast<ushort4*>(vp + 8 * qd) = o;
        }
      } else {
        bool msk = (MODE == 2) ? (mrow[gn] == 0) : false;
#pragma unroll
        for (int r = 0; r < 16; r++) {
          int row = (r & 3) + 8 * (r >> 2) + 4 * half;
          float val = acc[i][j][r] + bv;
          size_t off = (size_t)bz * strideC + (size_t)(gmb + row) * ldc + gn;
          if (MODE == 2) {
            if (msk) val = -1e20f;
            val = __expf(val * 0.03125f);  // mask BEFORE 1/sqrt(1024) scale, per ref
            rs[r] += val;
            ((unsigned short*)Cv)[off] = f2bf(val);
          } else {
            ((unsigned short*)Cv)[off] = f2bf(val);
          }
        }
      }
    }
    if (MODE == 2) {
      float* srowp = sums + (size_t)bz * 2048;
#pragma unroll
      for (int r = 0; r < 16; r++) {
        float v = rs[r];
#pragma unroll
        for (int o = 16; o >= 1; o >>= 1) v += __shfl_xor(v, o, 64);
        if (r31 == 0) {
          int row = (r & 3) + 8 * (r >> 2) + 4 * half;
          atomicAdd(&srowp[gmb + row], v);
        }
      }
    }
  }
}

// ================= 128x128 kernel (R0 core + R3 swizzle fix) for PV + out-proj =================
// Swizzle: rows are 128 B (8 slots); slot s of row r holds chunk s ^ ((r>>1)&7);
// a 16-lane read group covers all 16 combos of (row&1, slot) = 256 distinct bytes.
template<int MODE>
__global__ __launch_bounds__(256, 2) void gemm_bt128(
    const unsigned short* __restrict__ A, long lda, long strideA,
    const unsigned short* __restrict__ B, long ldb, long strideB,
    void* __restrict__ Cv, long ldc, long strideC,
    const float* __restrict__ bias, const int* __restrict__ mask,
    float* __restrict__ sums, unsigned short* __restrict__ vt, int K) {
  __shared__ unsigned short sA[128 * 64];
  __shared__ unsigned short sB[128 * 64];
  const int t = threadIdx.x;
  const int lane = t & 63;
  const int wave = t >> 6;

  const unsigned short* Ab = A + (size_t)blockIdx.z * strideA + (size_t)blockIdx.y * 128 * lda;
  const unsigned short* Bb = B + (size_t)blockIdx.z * strideB + (size_t)blockIdx.x * 128 * ldb;

  const int srow = t >> 3;
  const int schunk = (t & 7) ^ ((srow >> 1) & 7);   // R3: row-pair swizzle (was srow&7)
  const unsigned short* aptr = Ab + (size_t)srow * lda + schunk * 8;
  const unsigned short* bptr = Bb + (size_t)srow * ldb + schunk * 8;
  char* ldsA0 = (char*)&sA[0] + wave * 1024;
  char* ldsB0 = (char*)&sB[0] + wave * 1024;

  f32x16 acc[2][2];
#pragma unroll
  for (int i = 0; i < 2; i++)
#pragma unroll
    for (int j = 0; j < 2; j++)
#pragma unroll
      for (int r = 0; r < 16; r++) acc[i][j][r] = 0.f;

  const int wm = (wave >> 1) * 64;
  const int wn = (wave & 1) * 64;
  const int r31 = lane & 31;
  const int half = lane >> 5;
  const int swz = (r31 >> 1) & 7;   // R3: was r31&7

  int offA[2][4], offB[2][4];
#pragma unroll
  for (int i = 0; i < 2; i++)
#pragma unroll
    for (int s = 0; s < 4; s++) {
      offA[i][s] = (wm + i * 32 + r31) * 128 + (((2 * s + half) ^ swz) * 16);
      offB[i][s] = (wn + i * 32 + r31) * 128 + (((2 * s + half) ^ swz) * 16);
    }

  for (int k0 = 0; k0 < K; k0 += 64) {
    __syncthreads();
#pragma unroll
    for (int o = 0; o < 4; o++) {
      __builtin_amdgcn_global_load_lds((AS1 void*)(aptr + (size_t)o * 32 * lda + k0),
                                       (AS3 void*)(ldsA0 + o * 4096), 16, 0, 0);
      __builtin_amdgcn_global_load_lds((AS1 void*)(bptr + (size_t)o * 32 * ldb + k0),
                                       (AS3 void*)(ldsB0 + o * 4096), 16, 0, 0);
    }
    __syncthreads();
#pragma unroll
    for (int s = 0; s < 4; s++) {
      bf16x8 af[2], bfv[2];
#pragma unroll
      for (int i = 0; i < 2; i++) {
        af[i]  = *reinterpret_cast<const bf16x8*>((const char*)sA + offA[i][s]);
        bfv[i] = *reinterpret_cast<const bf16x8*>((const char*)sB + offB[i][s]);
      }
#pragma unroll
      for (int i = 0; i < 2; i++)
#pragma unroll
        for (int j = 0; j < 2; j++)
          acc[i][j] = __builtin_amdgcn_mfma_f32_32x32x16_bf16(af[i], bfv[j], acc[i][j], 0, 0, 0);
    }
  }

  // ---- epilogue ----
#pragma unroll
  for (int i = 0; i < 2; i++) {
    int gmb = blockIdx.y * 128 + wm + i * 32;
    float inv_r[16];
    if (MODE == 3) {
#pragma unroll
      for (int r = 0; r < 16; r++) {
        int row = (r & 3) + 8 * (r >> 2) + 4 * half;
        inv_r[r] = 1.0f / sums[(size_t)blockIdx.z * 2048 + gmb + row];
      }
    }
#pragma unroll
    for (int j = 0; j < 2; j++) {
      int gn = blockIdx.x * 128 + wn + j * 32 + r31;
      float bv = (MODE == 0) ? bias[gn] : 0.0f;
#pragma unroll
      for (int r = 0; r < 16; r++) {
        int row = (r & 3) + 8 * (r >> 2) + 4 * half;
        float val = acc[i][j][r] + bv;
        size_t off = (size_t)blockIdx.z * strideC + (size_t)(gmb + row) * ldc + gn;
        if (MODE == 3) {
          ((unsigned short*)Cv)[off] = f2bf(val * inv_r[r]);
        } else {
          ((float*)Cv)[off] = val;
        }
      }
    }
  }
}

extern "C" void kernel_launch(void* const* d_in, const int* in_sizes, int n_in,
                              void* d_out, int out_size, void* d_ws, size_t ws_size,
                              hipStream_t stream) {
  const float* X = (const float*)d_in[0];
  const int* mask = (const int*)d_in[1];
  const float* W_in = (const float*)d_in[2];
  const float* b_in = (const float*)d_in[3];
  const float* W_out = (const float*)d_in[4];
  const float* b_out = (const float*)d_in[5];
  float* out = (float*)d_out;

  const int S = 2048, D = 1024;
  // ws layout (bytes):
  //   Xb  [8192x1024] bf16  16777216  (reused as Ob after QKV)
  //   Wib [3072x1024] bf16   6291456
  //   Wob [1024x1024] bf16   2097152
  //   QK  [8192x2048] bf16  33554432  (Q cols 0..1023, K cols 1024..2047)
  //   P   [4x2048x2048] bf16 33554432 (unnormalized exp weights)
  //   Vt  [4x1024x2048] bf16 16777216
  //   sums[8192] f32            32768
  char* w = (char*)d_ws;
  unsigned short* Xb  = (unsigned short*)w;
  unsigned short* Wib = (unsigned short*)(w + 16777216);
  unsigned short* Wob = (unsigned short*)(w + 16777216 + 6291456);
  unsigned short* QK  = (unsigned short*)(w + 25165824);
  unsigned short* P   = (unsigned short*)(w + 58720256);
  unsigned short* Vt  = (unsigned short*)(w + 92274688);
  float*          sums = (float*)(w + 109051904);
  unsigned short* Ob  = Xb;

  // zero the row-sum accumulators (ws is re-poisoned before every call)
  hipMemsetAsync(sums, 0, 8192 * sizeof(float), stream);

  // one merged cast: X, W_in, W_out -> bf16 (outputs contiguous)
  cast_all_kernel<<<12288, 256, 0, stream>>>(X, W_in, W_out, Xb);

  // QKV = Xb @ W_in^T + b_in; Q,K -> QK[8192x2048], V -> Vt (transposed in epilogue)
  gemmQ<1><<<dim3(12, 32, 1), 512, 0, stream>>>(
      Xb, D, 0, Wib, D, 0, QK, 2048, 0, b_in, nullptr, nullptr, Vt, D);
  // P = exp(mask(Q K^T)/32); sums += fp32 row sums   [per batch 2048x2048]
  gemmQ<2><<<dim3(8, 8, 4), 512, 0, stream>>>(
      QK, 2048, (long)S * 2048, QK + 1024, 2048, (long)S * 2048,
      P, S, (long)S * S, nullptr, mask, sums, nullptr, D);
  // O = (P @ Vt^T) / sums   [per batch 2048x1024] bf16
  gemm_bt128<3><<<dim3(8, 16, 4), 256, 0, stream>>>(
      P, S, (long)S * S, Vt, S, (long)D * S,
      Ob, D, (long)S * D, nullptr, nullptr, sums, nullptr, S);
  // out = O @ W_out^T + b_out  [8192x1024] fp32
  gemm_bt128<0><<<dim3(8, 64, 1), 256, 0, stream>>>(
      Ob, D, 0, Wob, D, 0, out, D, 0, b_out, nullptr, nullptr, nullptr, D);
}

// Round 4
// 291.486 us; speedup vs baseline: 1.0900x; 1.0566x over previous
//
#include <hip/hip_runtime.h>
#include <stdint.h>

#define AS1 __attribute__((address_space(1)))
#define AS3 __attribute__((address_space(3)))

typedef __bf16 bf16x8 __attribute__((ext_vector_type(8)));
typedef float f32x16 __attribute__((ext_vector_type(16)));

__device__ __forceinline__ unsigned short f2bf(float f) {
  unsigned u = __float_as_uint(f);
  u += 0x7FFF + ((u >> 16) & 1);   // round-to-nearest-even
  return (unsigned short)(u >> 16);
}

// ---------------- merged fp32 -> bf16 cast for X, W_in, W_out (grid-stride) ----------------
__global__ __launch_bounds__(256) void cast_all_kernel(const float* __restrict__ X,
                                                       const float* __restrict__ Wi,
                                                       const float* __restrict__ Wo,
                                                       unsigned short* __restrict__ out) {
  const int c1 = 2097152;            // X groups of 4
  const int c2 = 786432;             // W_in groups
  const int c3 = 262144;             // W_out groups
  const int total = c1 + c2 + c3;
  for (int i = blockIdx.x * 256 + threadIdx.x; i < total; i += 2048 * 256) {
    const float* src;
    int j = i;
    if (i < c1) src = X;
    else if (i < c1 + c2) { src = Wi; j = i - c1; }
    else { src = Wo; j = i - c1 - c2; }
    float4 v = reinterpret_cast<const float4*>(src)[j];
    ushort4 o;
    o.x = f2bf(v.x); o.y = f2bf(v.y); o.z = f2bf(v.z); o.w = f2bf(v.w);
    reinterpret_cast<ushort4*>(out)[i] = o;
  }
}

// ---------------- GEMM-BT 128x128 (R0-proven core + conflict-free swizzle) ----------------
// C[m][n] = sum_k A[m][k]*B[n][k]. BK=64, 4 waves of 2x2 32x32x16 MFMA,
// global_load_lds staging, row-pair XOR chunk swizzle (R3-verified: conflicts -> 0).
// MODE 0: fp32 out, +bias                                  (out-proj)
// MODE 1: bf16 out, +bias; blocks bx>=16 write V^T into vt (QKV + transpose)
// MODE 2: bf16 out = exp((mask? -1e20 : val)/32); row sums of fp32 exp
//         reduced cross-lane and atomically added into sums (QK^T + softmax top)
// MODE 3: bf16 out = val / sums[row]                       (PV + softmax normalize)
template<int MODE>
__global__ __launch_bounds__(256, 2) void gemm_bt128(
    const unsigned short* __restrict__ A, long lda, long strideA,
    const unsigned short* __restrict__ B, long ldb, long strideB,
    void* __restrict__ Cv, long ldc, long strideC,
    const float* __restrict__ bias, const int* __restrict__ mask,
    float* __restrict__ sums, unsigned short* __restrict__ vt, int K) {
  __shared__ unsigned short sA[128 * 64];
  __shared__ unsigned short sB[128 * 64];
  const int t = threadIdx.x;
  const int lane = t & 63;
  const int wave = t >> 6;

  const unsigned short* Ab = A + (size_t)blockIdx.z * strideA + (size_t)blockIdx.y * 128 * lda;
  const unsigned short* Bb = B + (size_t)blockIdx.z * strideB + (size_t)blockIdx.x * 128 * ldb;

  const int srow = t >> 3;
  const int schunk = (t & 7) ^ ((srow >> 1) & 7);   // conflict-free: row-PAIR swizzle
  const unsigned short* aptr = Ab + (size_t)srow * lda + schunk * 8;
  const unsigned short* bptr = Bb + (size_t)srow * ldb + schunk * 8;
  char* ldsA0 = (char*)&sA[0] + wave * 1024;
  char* ldsB0 = (char*)&sB[0] + wave * 1024;

  f32x16 acc[2][2];
#pragma unroll
  for (int i = 0; i < 2; i++)
#pragma unroll
    for (int j = 0; j < 2; j++)
#pragma unroll
      for (int r = 0; r < 16; r++) acc[i][j][r] = 0.f;

  const int wm = (wave >> 1) * 64;
  const int wn = (wave & 1) * 64;
  const int r31 = lane & 31;
  const int half = lane >> 5;
  const int swz = (r31 >> 1) & 7;   // conflict-free read-side swizzle (was r31&7)

  int offA[2][4], offB[2][4];
#pragma unroll
  for (int i = 0; i < 2; i++)
#pragma unroll
    for (int s = 0; s < 4; s++) {
      offA[i][s] = (wm + i * 32 + r31) * 128 + (((2 * s + half) ^ swz) * 16);
      offB[i][s] = (wn + i * 32 + r31) * 128 + (((2 * s + half) ^ swz) * 16);
    }

  for (int k0 = 0; k0 < K; k0 += 64) {
    __syncthreads();
#pragma unroll
    for (int o = 0; o < 4; o++) {
      __builtin_amdgcn_global_load_lds((AS1 void*)(aptr + (size_t)o * 32 * lda + k0),
                                       (AS3 void*)(ldsA0 + o * 4096), 16, 0, 0);
      __builtin_amdgcn_global_load_lds((AS1 void*)(bptr + (size_t)o * 32 * ldb + k0),
                                       (AS3 void*)(ldsB0 + o * 4096), 16, 0, 0);
    }
    __syncthreads();
#pragma unroll
    for (int s = 0; s < 4; s++) {
      bf16x8 af[2], bfv[2];
#pragma unroll
      for (int i = 0; i < 2; i++) {
        af[i]  = *reinterpret_cast<const bf16x8*>((const char*)sA + offA[i][s]);
        bfv[i] = *reinterpret_cast<const bf16x8*>((const char*)sB + offB[i][s]);
      }
#pragma unroll
      for (int i = 0; i < 2; i++)
#pragma unroll
        for (int j = 0; j < 2; j++)
          acc[i][j] = __builtin_amdgcn_mfma_f32_32x32x16_bf16(af[i], bfv[j], acc[i][j], 0, 0, 0);
    }
  }

  // ---- epilogue ----
  const int* mrow = (MODE == 2) ? (mask + (size_t)blockIdx.z * 2048) : nullptr;
  const bool vblock = (MODE == 1) && (blockIdx.x >= 16);  // QKV: n>=2048 is the V third
  float rs[2][16];  // MODE 2: per-lane partial row sums (over this block's 128 cols)

#pragma unroll
  for (int i = 0; i < 2; i++) {
    int gmb = blockIdx.y * 128 + wm + i * 32;
    float inv_r[16];
    if (MODE == 3) {
#pragma unroll
      for (int r = 0; r < 16; r++) {
        int row = (r & 3) + 8 * (r >> 2) + 4 * half;
        inv_r[r] = 1.0f / sums[(size_t)blockIdx.z * 2048 + gmb + row];
      }
    }
    if (MODE == 2) {
#pragma unroll
      for (int r = 0; r < 16; r++) rs[i][r] = 0.f;
    }
#pragma unroll
    for (int j = 0; j < 2; j++) {
      int gn = blockIdx.x * 128 + wn + j * 32 + r31;
      float bv = (MODE == 0 || MODE == 1) ? bias[gn] : 0.0f;
      if (MODE == 1 && vblock) {
        // write V^T: Vt[b][d][s], d = gn-2048, s = gmb+row
        int b = gmb >> 11;
        int sbase = gmb & 2047;
        int d = gn - 2048;
        unsigned short* vp = vt + (size_t)b * 1024 * 2048 + (size_t)d * 2048 + sbase + 4 * half;
#pragma unroll
        for (int qd = 0; qd < 4; qd++) {
          ushort4 o;
          o.x = f2bf(acc[i][j][4 * qd + 0] + bv);
          o.y = f2bf(acc[i][j][4 * qd + 1] + bv);
          o.z = f2bf(acc[i][j][4 * qd + 2] + bv);
          o.w = f2bf(acc[i][j][4 * qd + 3] + bv);
          *reinterpret_cast<ushort4*>(vp + 8 * qd) = o;
        }
      } else {
        bool msk = (MODE == 2) ? (mrow[gn] == 0) : false;
#pragma unroll
        for (int r = 0; r < 16; r++) {
          int row = (r & 3) + 8 * (r >> 2) + 4 * half;
          float val = acc[i][j][r] + bv;
          size_t off = (size_t)blockIdx.z * strideC + (size_t)(gmb + row) * ldc + gn;
          if (MODE == 2) {
            if (msk) val = -1e20f;
            val = __expf(val * 0.03125f);  // mask BEFORE 1/sqrt(1024) scale, per ref
            rs[i][r] += val;
            ((unsigned short*)Cv)[off] = f2bf(val);
          } else if (MODE == 3) {
            ((unsigned short*)Cv)[off] = f2bf(val * inv_r[r]);
          } else if (MODE == 1) {
            ((unsigned short*)Cv)[off] = f2bf(val);
          } else {
            ((float*)Cv)[off] = val;
          }
        }
      }
    }
  }

  if (MODE == 2) {
    // reduce rs over the 32 column-lanes (r31), then one atomicAdd per row.
    float* srow2 = sums + (size_t)blockIdx.z * 2048;
#pragma unroll
    for (int i = 0; i < 2; i++) {
      int gmb = blockIdx.y * 128 + wm + i * 32;
#pragma unroll
      for (int r = 0; r < 16; r++) {
        float v = rs[i][r];
#pragma unroll
        for (int o = 16; o >= 1; o >>= 1) v += __shfl_xor(v, o, 64);
        if (r31 == 0) {
          int row = (r & 3) + 8 * (r >> 2) + 4 * half;
          atomicAdd(&srow2[gmb + row], v);
        }
      }
    }
  }
}

extern "C" void kernel_launch(void* const* d_in, const int* in_sizes, int n_in,
                              void* d_out, int out_size, void* d_ws, size_t ws_size,
                              hipStream_t stream) {
  const float* X = (const float*)d_in[0];
  const int* mask = (const int*)d_in[1];
  const float* W_in = (const float*)d_in[2];
  const float* b_in = (const float*)d_in[3];
  const float* W_out = (const float*)d_in[4];
  const float* b_out = (const float*)d_in[5];
  float* out = (float*)d_out;

  const int S = 2048, D = 1024;
  // ws layout (bytes):
  //   Xb  [8192x1024] bf16  16777216  (reused as Ob after QKV)
  //   Wib [3072x1024] bf16   6291456
  //   Wob [1024x1024] bf16   2097152
  //   QK  [8192x2048] bf16  33554432  (Q cols 0..1023, K cols 1024..2047)
  //   P   [4x2048x2048] bf16 33554432 (unnormalized exp weights)
  //   Vt  [4x1024x2048] bf16 16777216
  //   sums[8192] f32            32768
  char* w = (char*)d_ws;
  unsigned short* Xb  = (unsigned short*)w;
  unsigned short* Wib = (unsigned short*)(w + 16777216);
  unsigned short* Wob = (unsigned short*)(w + 16777216 + 6291456);
  unsigned short* QK  = (unsigned short*)(w + 25165824);
  unsigned short* P   = (unsigned short*)(w + 58720256);
  unsigned short* Vt  = (unsigned short*)(w + 92274688);
  float*          sums = (float*)(w + 109051904);
  unsigned short* Ob  = Xb;

  // zero the row-sum accumulators (ws is re-poisoned before every call)
  hipMemsetAsync(sums, 0, 8192 * sizeof(float), stream);

  // one merged cast: X, W_in, W_out -> bf16 (outputs contiguous), grid-stride
  cast_all_kernel<<<2048, 256, 0, stream>>>(X, W_in, W_out, Xb);

  // QKV = Xb @ W_in^T + b_in; Q,K -> QK[8192x2048], V -> Vt (transposed in epilogue)
  gemm_bt128<1><<<dim3(24, 64, 1), 256, 0, stream>>>(
      Xb, D, 0, Wib, D, 0, QK, 2048, 0, b_in, nullptr, nullptr, Vt, D);
  // P = exp(mask(Q K^T)/32); sums += row sums of fp32 exp  [per batch 2048x2048]
  gemm_bt128<2><<<dim3(16, 16, 4), 256, 0, stream>>>(
      QK, 2048, (long)S * 2048, QK + 1024, 2048, (long)S * 2048,
      P, S, (long)S * S, nullptr, mask, sums, nullptr, D);
  // O = (P @ Vt^T) / sums   [per batch 2048x1024] bf16
  gemm_bt128<3><<<dim3(8, 16, 4), 256, 0, stream>>>(
      P, S, (long)S * S, Vt, S, (long)D * S,
      Ob, D, (long)S * D, nullptr, nullptr, sums, nullptr, S);
  // out = O @ W_out^T + b_out  [8192x1024] fp32
  gemm_bt128<0><<<dim3(8, 64, 1), 256, 0, stream>>>(
      Ob, D, 0, Wob, D, 0, out, D, 0, b_out, nullptr, nullptr, nullptr, D);
}